// Round 8
// baseline (38.056 us; speedup 1.0000x reference)
//
#include <hip/hip_runtime.h>
#include <stdint.h>

#define BTOT 8192
#define NSS  4096
#define LL   64
#define BT   128           // batches per block (4 waves x 32)
#define WB   32            // batches per wave
#define STT  32            // states per tile
#define NT   (NSS/STT)     // 128 state tiles total
#define NSPLIT 8           // state splits across blocks
#define TPS  (NT/NSPLIT)   // 16 tiles per split; ALL waves of a block sweep all of them
#define JROWB 80           // padded LDS row bytes for J tile
#define JBUFB (32 * JROWB) // one J buffer: 2560 B

typedef __bf16    bf16x8 __attribute__((ext_vector_type(8)));
typedef _Float16  f16x8  __attribute__((ext_vector_type(8)));
typedef float     f32x4  __attribute__((ext_vector_type(4)));

static __device__ __forceinline__ unsigned short f2bf(float x){
  union { float f; uint32_t u; } v; v.f = x;
  uint32_t r = v.u + 0x7fffu + ((v.u >> 16) & 1u);
  return (unsigned short)(r >> 16);
}

// Pack S into MFMA-fragment order (unchanged from round 6):
//  Sp  (f16):  GEMM1 A-frags. item (t, frag=ss*2+kc, lane): j -> S[t*32+ss*16+(lane&15)][kc*32+(lane>>4)*8+j]
//  STp (bf16): GEMM2 A-frags. item (t, lt, lane):          j -> S[t*32+(lane>>4)*8+j][lt*16+(lane&15)]
__global__ void prepack_kernel(const float* __restrict__ S,
                               _Float16* __restrict__ Sp,
                               unsigned short* __restrict__ STp){
  const int t = blockIdx.x;
  const int sbase = t * STT;
  #pragma unroll
  for (int rep = 0; rep < 2; ++rep){
    int item = rep * 256 + threadIdx.x;    // 0..511
    int frag = item >> 6;                  // 0..7
    int lane = item & 63;
    int c16 = lane & 15, q4 = lane >> 4;
    if (frag < 4){
      int ss = frag >> 1, kc = frag & 1;
      const float* row = S + (size_t)(sbase + ss*16 + c16)*LL + kc*32 + q4*8;
      f16x8 h;
      #pragma unroll
      for (int j = 0; j < 8; ++j) h[j] = (_Float16)row[j];   // 0/1 exact
      *(f16x8*)&Sp[((size_t)(t*4 + frag)*64 + lane)*8] = h;
    } else {
      int lt = frag - 4;
      int l  = lt*16 + c16;
      int s0 = sbase + q4*8;
      union { unsigned short u[8]; bf16x8 v; } H;
      #pragma unroll
      for (int j = 0; j < 8; ++j) H.u[j] = f2bf(S[(size_t)(s0 + j)*LL + l]);  // 0/1 exact
      *(bf16x8*)&STp[((size_t)(t*4 + lt)*64 + lane)*8] = H.v;
    }
  }
}

// Waves split BATCHES and share tiles: each wave owns 32 batches and sweeps all
// TPS tiles of this block's state split -> acc2 is complete for (split, batches),
// no cross-wave reduction, no barriers anywhere.
__launch_bounds__(256, 2)
__global__ void fused_kernel(const float* __restrict__ f,
                             const _Float16* __restrict__ Sp,
                             const unsigned short* __restrict__ STp,
                             float* __restrict__ numPart,   // [NSPLIT][BTOT][LL]
                             float* __restrict__ zPart){    // [NSPLIT][BTOT]
  const int tid  = threadIdx.x;
  const int w    = tid >> 6;
  const int lane = tid & 63;
  const int c16  = lane & 15;
  const int q4   = lane >> 4;
  const int bt   = blockIdx.x & 63;          // 64 batch-blocks
  const int sp   = blockIdx.x >> 6;          // state split 0..7
  const int bb   = bt * BT + w * WB;         // this wave's batch base

  __shared__ unsigned char jraw[4][2][JBUFB];   // per-wave double J buffers, 20.5 KB
  unsigned char* jb0 = &jraw[w][0][0];
  unsigned char* jb1 = &jraw[w][1][0];

  // ---- prologue: f B-fragments in f16 (register-resident) ----
  // B-frag layout: col = lane&15 (batch), k = (lane>>4)*8 + j (label)
  f16x8 fB[2][2];
  #pragma unroll
  for (int g = 0; g < 2; ++g){
    const float* frow = f + (size_t)(bb + g*16 + c16) * LL;
    #pragma unroll
    for (int kc = 0; kc < 2; ++kc){
      float vv[8];
      *(float4*)&vv[0] = *(const float4*)&frow[kc*32 + 8*q4];
      *(float4*)&vv[4] = *(const float4*)&frow[kc*32 + 8*q4 + 4];
      f16x8 h;
      #pragma unroll
      for (int j = 0; j < 8; ++j) h[j] = (_Float16)vv[j];
      fB[g][kc] = h;
    }
  }

  f32x4 acc2[4][2];
  #pragma unroll
  for (int lt = 0; lt < 4; ++lt)
    #pragma unroll
    for (int g = 0; g < 2; ++g) acc2[lt][g] = (f32x4){0.f,0.f,0.f,0.f};
  float zpart[2] = {0.f, 0.f};

  // ---- software-pipelined sweep of the split's 16 tiles (all waves same tiles) ----
  const int tb = sp * TPS;
  f16x8  a1[2][4];
  bf16x8 a2[2][4];
  {
    const _Float16* ps = Sp + ((size_t)(tb*4)*64 + lane)*8;
    #pragma unroll
    for (int k = 0; k < 4; ++k) a1[0][k] = *(const f16x8*)(ps + (size_t)k*64*8);
  }

  #pragma unroll
  for (int t = 0; t < TPS; ++t){
    const int cur = t & 1, nxt = cur ^ 1;
    unsigned char* jcur = cur ? jb1 : jb0;
    unsigned char* jprv = cur ? jb0 : jb1;

    // GEMM1: potential tile t (f16)
    f32x4 p_[2][2];
    #pragma unroll
    for (int ss = 0; ss < 2; ++ss)
      #pragma unroll
      for (int g = 0; g < 2; ++g){
        f32x4 a = (f32x4){0.f,0.f,0.f,0.f};
        a = __builtin_amdgcn_mfma_f32_16x16x32_f16(a1[cur][ss*2+0], fB[g][0], a, 0,0,0);
        a = __builtin_amdgcn_mfma_f32_16x16x32_f16(a1[cur][ss*2+1], fB[g][1], a, 0,0,0);
        p_[ss][g] = a;
      }

    // prefetch a1 for tile t+1
    if (t < TPS-1){
      const _Float16* ps = Sp + ((size_t)((tb+t+1)*4)*64 + lane)*8;
      #pragma unroll
      for (int k = 0; k < 4; ++k) a1[nxt][k] = *(const f16x8*)(ps + (size_t)k*64*8);
    }

    // exp -> z -> pack bf16 -> jb[cur]
    #pragma unroll
    for (int ss = 0; ss < 2; ++ss)
      #pragma unroll
      for (int g = 0; g < 2; ++g){
        float J0 = __expf(p_[ss][g][0]);
        float J1 = __expf(p_[ss][g][1]);
        float J2 = __expf(p_[ss][g][2]);
        float J3 = __expf(p_[ss][g][3]);
        zpart[g] += (J0 + J1) + (J2 + J3);
        union { __bf16 h[4]; uint2 u2; } P_;
        P_.h[0] = (__bf16)J0; P_.h[1] = (__bf16)J1;
        P_.h[2] = (__bf16)J2; P_.h[3] = (__bf16)J3;
        *(uint2*)&jcur[(g*16 + c16)*JROWB + ss*32 + q4*8] = P_.u2;
      }

    // GEMM2 for tile t-1 (J written a full iteration ago)
    if (t > 0){
      bf16x8 b2[2];
      #pragma unroll
      for (int g = 0; g < 2; ++g)
        b2[g] = *(const bf16x8*)&jprv[(g*16 + c16)*JROWB + q4*16];
      #pragma unroll
      for (int lt = 0; lt < 4; ++lt)
        #pragma unroll
        for (int g = 0; g < 2; ++g)
          acc2[lt][g] = __builtin_amdgcn_mfma_f32_16x16x32_bf16(a2[nxt][lt], b2[g], acc2[lt][g], 0,0,0);
    }

    // prefetch a2 for tile t (consumed next iteration / drain)
    {
      const unsigned short* pt = STp + ((size_t)((tb+t)*4)*64 + lane)*8;
      #pragma unroll
      for (int lt = 0; lt < 4; ++lt)
        a2[cur][lt] = *(const bf16x8*)(pt + (size_t)lt*64*8);
    }
  }

  // drain: GEMM2 for the last tile (TPS-1 is odd -> jb1 / a2[1])
  {
    bf16x8 b2[2];
    #pragma unroll
    for (int g = 0; g < 2; ++g)
      b2[g] = *(const bf16x8*)&jb1[(g*16 + c16)*JROWB + q4*16];
    #pragma unroll
    for (int lt = 0; lt < 4; ++lt)
      #pragma unroll
      for (int g = 0; g < 2; ++g)
        acc2[lt][g] = __builtin_amdgcn_mfma_f32_16x16x32_bf16(a2[1][lt], b2[g], acc2[lt][g], 0,0,0);
  }

  // ---- epilogue: direct register->global stores, shuffle-reduced z. No LDS, no barriers. ----
  // acc2 D layout: col = c16 (batch within group g), row = q4*4+jj (label within lt*16)
  float* numOut = numPart + (size_t)sp * BTOT * LL + (size_t)bb * LL;
  #pragma unroll
  for (int lt = 0; lt < 4; ++lt)
    #pragma unroll
    for (int g = 0; g < 2; ++g)
      *(f32x4*)&numOut[(size_t)(g*16 + c16)*LL + lt*16 + q4*4] = acc2[lt][g];

  #pragma unroll
  for (int g = 0; g < 2; ++g){
    float zz = zpart[g];
    zz += __shfl_down(zz, 32);
    zz += __shfl_down(zz, 16);
    if (lane < 16) zPart[(size_t)sp * BTOT + bb + g*16 + lane] = zz;
  }
}

// finalize: sum split partials, p = num/z, BCE, per-block loss partials
__global__ void finalize_kernel(const float* __restrict__ numPart,
                                const float* __restrict__ zPart,
                                const float* __restrict__ y,
                                const float* __restrict__ mask,
                                float* __restrict__ out,     // [1 + BTOT*LL]
                                float* __restrict__ parts){  // [2048]
  int tid = threadIdx.x;
  int idx = blockIdx.x * 256 + tid;      // 0 .. BTOT*LL-1
  int b = idx >> 6;
  float num = 0.f, z = 0.f;
  #pragma unroll
  for (int sp = 0; sp < NSPLIT; ++sp){
    num += numPart[(size_t)sp * BTOT * LL + idx];
    z   += zPart[(size_t)sp * BTOT + b];
  }
  float p = fminf(num / z, 1.0f);
  out[1 + idx] = p;
  float lg = fmaxf(__logf(p), -100.f);
  float l1 = fmaxf(log1pf(-p), -100.f);
  float yv = y[idx], mv = mask[idx];
  float lsum = -(yv*lg + (1.f - yv)*l1) * mv;
  #pragma unroll
  for (int off = 32; off; off >>= 1) lsum += __shfl_down(lsum, off);
  __shared__ float wred[4];
  int w = tid >> 6, lane = tid & 63;
  if (lane == 0) wred[w] = lsum;
  __syncthreads();
  if (tid == 0) parts[blockIdx.x] = (wred[0] + wred[1]) + (wred[2] + wred[3]);
}

__global__ void loss_kernel(const float* __restrict__ parts, float* __restrict__ out){
  float v = 0.f;
  #pragma unroll
  for (int i = 0; i < 8; ++i) v += parts[threadIdx.x + 256*i];
  #pragma unroll
  for (int off = 32; off; off >>= 1) v += __shfl_down(v, off);
  __shared__ float sred[4];
  int w = threadIdx.x >> 6, lane = threadIdx.x & 63;
  if (lane == 0) sred[w] = v;
  __syncthreads();
  if (threadIdx.x == 0)
    out[0] = ((sred[0] + sred[1]) + (sred[2] + sred[3])) * (1.0f / ((float)BTOT * (float)LL));
}

extern "C" void kernel_launch(void* const* d_in, const int* in_sizes, int n_in,
                              void* d_out, int out_size, void* d_ws, size_t ws_size,
                              hipStream_t stream){
  const float* f = (const float*)d_in[0];
  const float* y = (const float*)d_in[1];
  const float* m = (const float*)d_in[2];
  const float* S = (const float*)d_in[3];
  float* out = (float*)d_out;

  _Float16* Sp        = (_Float16*)d_ws;                               // 512 KB
  unsigned short* STp = (unsigned short*)(Sp + (size_t)NT*4*64*8);     // 512 KB
  char* p = (char*)d_ws + (size_t)2 * NT * 4 * 64 * 8 * 2;
  float* numPart = (float*)p;  p += (size_t)NSPLIT * BTOT * LL * sizeof(float);  // 16 MB
  float* zPart   = (float*)p;  p += (size_t)NSPLIT * BTOT * sizeof(float);       // 256 KB
  float* parts   = (float*)p;                                                    // 8 KB

  prepack_kernel<<<NT, 256, 0, stream>>>(S, Sp, STp);
  fused_kernel<<<(BTOT/BT) * NSPLIT, 256, 0, stream>>>(f, Sp, STp, numPart, zPart);
  finalize_kernel<<<(BTOT*LL)/256, 256, 0, stream>>>(numPart, zPart, y, m, out, parts);
  loss_kernel<<<1, 256, 0, stream>>>(parts, out);
}